// Round 1
// baseline (167.953 us; speedup 1.0000x reference)
//
#include <hip/hip_runtime.h>

// ComplexMixture: B=32, S=8192, D=64, fp32 in/out.
// out_real = (R^T R + I^T I)/S   [B,64,64]
// out_imag = (R^T I - (R^T I)^T)/S
// Strategy: bf16 MFMA Gram with split-K partials in d_ws + reduce kernel.

#define BATCH 32
#define SEQ   8192
#define DD    64
#define CHUNKS 16
#define SCHUNK (SEQ / CHUNKS)   // 512
#define BK     128
#define NIT    (SCHUNK / BK)    // 4

typedef __bf16 bf16x8 __attribute__((ext_vector_type(8)));
typedef float  f32x16 __attribute__((ext_vector_type(16)));

__device__ __forceinline__ unsigned bf16pk(float a, float b) {
  unsigned ua = __builtin_bit_cast(unsigned, a);
  unsigned ub = __builtin_bit_cast(unsigned, b);
  ua = (ua + 0x7fffu + ((ua >> 16) & 1u)) >> 16;   // RNE to bf16
  ub = (ub + 0x7fffu + ((ub >> 16) & 1u)) >> 16;
  return (ua & 0xffffu) | (ub << 16);
}

// lds[0..15][64]  = R tile, packed: lds[g][d] = 8 bf16 of R[s0+g*8 .. +8][d]
// lds[16..31][64] = I tile, same layout.
// Epilogue reuses the same 32 KB as float scratch for the ri transpose.
__global__ __launch_bounds__(256, 2) void gram_partial(
    const float* __restrict__ R, const float* __restrict__ I,
    float* __restrict__ ws)
{
  __shared__ uint4 lds[32][64];
  const int tid  = threadIdx.x;
  const int wave = tid >> 6;
  const int lane = tid & 63;
  const int b = blockIdx.x & 31;
  const int c = blockIdx.x >> 5;          // 0..15
  const float* Rb = R + (size_t)b * (SEQ * DD);
  const float* Ib = I + (size_t)b * (SEQ * DD);
  const int m0 = (wave >> 1) * 32;        // wave tile row base
  const int n0 = (wave & 1) * 32;         // wave tile col base
  const int l31 = lane & 31;
  const int lhi = lane >> 5;

  f32x16 accR = {};   // rr + ii
  f32x16 accI = {};   // ri

  const int chunk0 = c * SCHUNK;

  for (int it = 0; it < NIT; ++it) {
    const int sbase = chunk0 + it * BK;
    // ---- stage: transpose fp32 rows -> packed bf16 LDS ----
    #pragma unroll
    for (int gi = 0; gi < 4; ++gi) {
      const int g = gi * 4 + wave;        // 16 groups of 8 rows
      const float* pR = Rb + (size_t)(sbase + g * 8) * DD + lane;
      const float* pI = Ib + (size_t)(sbase + g * 8) * DD + lane;
      float r0 = pR[0*64], r1 = pR[1*64], r2 = pR[2*64], r3 = pR[3*64];
      float r4 = pR[4*64], r5 = pR[5*64], r6 = pR[6*64], r7 = pR[7*64];
      float i0 = pI[0*64], i1 = pI[1*64], i2 = pI[2*64], i3 = pI[3*64];
      float i4 = pI[4*64], i5 = pI[5*64], i6 = pI[6*64], i7 = pI[7*64];
      uint4 qR; qR.x = bf16pk(r0, r1); qR.y = bf16pk(r2, r3);
                qR.z = bf16pk(r4, r5); qR.w = bf16pk(r6, r7);
      uint4 qI; qI.x = bf16pk(i0, i1); qI.y = bf16pk(i2, i3);
                qI.z = bf16pk(i4, i5); qI.w = bf16pk(i6, i7);
      lds[g][lane]      = qR;   // ds_write_b128, contiguous per lane
      lds[16 + g][lane] = qI;
    }
    __syncthreads();
    // ---- compute: 8 k-steps of 16 ----
    #pragma unroll
    for (int ks = 0; ks < BK / 16; ++ks) {
      const int kg = ks * 2 + lhi;
      bf16x8 aR = __builtin_bit_cast(bf16x8, lds[kg][m0 + l31]);
      bf16x8 bR = __builtin_bit_cast(bf16x8, lds[kg][n0 + l31]);
      bf16x8 aI = __builtin_bit_cast(bf16x8, lds[16 + kg][m0 + l31]);
      bf16x8 bI = __builtin_bit_cast(bf16x8, lds[16 + kg][n0 + l31]);
      accR = __builtin_amdgcn_mfma_f32_32x32x16_bf16(aR, bR, accR, 0, 0, 0);
      accR = __builtin_amdgcn_mfma_f32_32x32x16_bf16(aI, bI, accR, 0, 0, 0);
      accI = __builtin_amdgcn_mfma_f32_32x32x16_bf16(aR, bI, accI, 0, 0, 0);
    }
    __syncthreads();
  }

  // ---- epilogue: write partials to workspace ----
  // ws layout: [(c*32+b)][2][64*64]; slot 0 = rr+ii, slot 1 = ri - ri^T
  float* wsR = ws + ((size_t)(c * 32 + b) * 2) * 4096;
  float* wsM = wsR + 4096;
  const int jj = n0 + l31;
  // C/D layout (32x32): col = n0 + (lane&31), row = (r&3) + 8*(r>>2) + 4*(lane>>5)
  #pragma unroll
  for (int r = 0; r < 16; ++r) {
    const int i = m0 + (r & 3) + 8 * (r >> 2) + 4 * lhi;
    wsR[i * 64 + jj] = accR[r];
  }
  // antisymmetrize ri within the block via padded LDS transpose
  float* ldsf = (float*)lds;   // need 64*65*4 = 16.6 KB <= 32 KB
  #pragma unroll
  for (int r = 0; r < 16; ++r) {
    const int i = m0 + (r & 3) + 8 * (r >> 2) + 4 * lhi;
    ldsf[i * 65 + jj] = accI[r];
  }
  __syncthreads();
  #pragma unroll
  for (int k = 0; k < 16; ++k) {
    const int e = tid + 256 * k;
    const int i = e >> 6, j = e & 63;
    wsM[e] = ldsf[i * 65 + j] - ldsf[j * 65 + i];
  }
}

// Sum the 16 chunk-partials, scale by 1/S, write final output.
// out layout: out_real [32][64][64] then out_imag [32][64][64] flat.
__global__ __launch_bounds__(256) void gram_reduce(
    const float* __restrict__ ws, float* __restrict__ out)
{
  const int gtid = blockIdx.x * 256 + threadIdx.x;
  const float inv = 1.0f / (float)SEQ;
  #pragma unroll
  for (int k = 0; k < 4; ++k) {
    const int o    = gtid + k * 65536;
    const int kind = o >> 17;          // 0=real, 1=imag
    const int rem  = o & 131071;
    const int b    = rem >> 12;
    const int e    = rem & 4095;
    float s = 0.0f;
    #pragma unroll
    for (int c = 0; c < CHUNKS; ++c)
      s += ws[((size_t)(c * 32 + b) * 2 + kind) * 4096 + e];
    out[o] = s * inv;
  }
}

extern "C" void kernel_launch(void* const* d_in, const int* in_sizes, int n_in,
                              void* d_out, int out_size, void* d_ws, size_t ws_size,
                              hipStream_t stream) {
  const float* R = (const float*)d_in[0];
  const float* I = (const float*)d_in[1];
  float* out = (float*)d_out;
  float* ws  = (float*)d_ws;   // uses 512 * 8192 * 4 B = 16.8 MB

  gram_partial<<<BATCH * CHUNKS, 256, 0, stream>>>(R, I, ws);
  gram_reduce<<<256, 256, 0, stream>>>(ws, out);
}

// Round 2
// 161.583 us; speedup vs baseline: 1.0394x; 1.0394x over previous
//
#include <hip/hip_runtime.h>

// ComplexMixture: B=32, S=8192, D=64, fp32 in/out.
// out_real = (R^T R + I^T I)/S   [B,64,64]
// out_imag = (R^T I - (R^T I)^T)/S
// bf16 MFMA Gram, split-K partials in d_ws + reduce kernel.
// R2: 4 blocks/CU (CHUNKS=32, ws-size-guarded) + hoisted 64-load burst per tile.

#define BATCH 32
#define SEQ   8192
#define DD    64
#define BK    128

typedef __bf16 bf16x8 __attribute__((ext_vector_type(8)));
typedef float  f32x16 __attribute__((ext_vector_type(16)));

__device__ __forceinline__ unsigned bf16pk(float a, float b) {
  unsigned ua = __builtin_bit_cast(unsigned, a);
  unsigned ub = __builtin_bit_cast(unsigned, b);
  ua = (ua + 0x7fffu + ((ua >> 16) & 1u)) >> 16;   // RNE to bf16
  ub = (ub + 0x7fffu + ((ub >> 16) & 1u)) >> 16;
  return (ua & 0xffffu) | (ub << 16);
}

// lds[0..15][64]  = R tile: lds[g][d] = 8 bf16 of R[s0+g*8 .. +8][d] (k-contig)
// lds[16..31][64] = I tile. Epilogue reuses as float scratch for ri transpose.
template<int CHUNKS>
__global__ __launch_bounds__(256, 4) void gram_partial(
    const float* __restrict__ R, const float* __restrict__ I,
    float* __restrict__ ws)
{
  constexpr int SCHUNK = SEQ / CHUNKS;
  constexpr int NIT    = SCHUNK / BK;
  __shared__ uint4 lds[32][64];
  const int tid  = threadIdx.x;
  const int wave = tid >> 6;
  const int lane = tid & 63;
  const int b = blockIdx.x & 31;
  const int c = blockIdx.x >> 5;
  const float* Rb = R + (size_t)b * (SEQ * DD);
  const float* Ib = I + (size_t)b * (SEQ * DD);
  const int m0 = (wave >> 1) * 32;
  const int n0 = (wave & 1) * 32;
  const int l31 = lane & 31;
  const int lhi = lane >> 5;

  f32x16 accR = {};   // rr + ii
  f32x16 accI = {};   // ri

  const int chunk0 = c * SCHUNK;

  for (int it = 0; it < NIT; ++it) {
    const int sbase = chunk0 + it * BK;
    // ---- stage: issue ALL 64 loads before packing (latency hiding) ----
    float rv[4][8], iv[4][8];
    #pragma unroll
    for (int gi = 0; gi < 4; ++gi) {
      const int g = gi * 4 + wave;
      const float* pR = Rb + (size_t)(sbase + g * 8) * DD + lane;
      const float* pI = Ib + (size_t)(sbase + g * 8) * DD + lane;
      #pragma unroll
      for (int j = 0; j < 8; ++j) { rv[gi][j] = pR[j * 64]; iv[gi][j] = pI[j * 64]; }
    }
    #pragma unroll
    for (int gi = 0; gi < 4; ++gi) {
      const int g = gi * 4 + wave;
      uint4 qR; qR.x = bf16pk(rv[gi][0], rv[gi][1]); qR.y = bf16pk(rv[gi][2], rv[gi][3]);
                qR.z = bf16pk(rv[gi][4], rv[gi][5]); qR.w = bf16pk(rv[gi][6], rv[gi][7]);
      uint4 qI; qI.x = bf16pk(iv[gi][0], iv[gi][1]); qI.y = bf16pk(iv[gi][2], iv[gi][3]);
                qI.z = bf16pk(iv[gi][4], iv[gi][5]); qI.w = bf16pk(iv[gi][6], iv[gi][7]);
      lds[g][lane]      = qR;   // ds_write_b128
      lds[16 + g][lane] = qI;
    }
    __syncthreads();
    // ---- compute: 8 k-steps of 16 ----
    #pragma unroll
    for (int ks = 0; ks < BK / 16; ++ks) {
      const int kg = ks * 2 + lhi;
      bf16x8 aR = __builtin_bit_cast(bf16x8, lds[kg][m0 + l31]);
      bf16x8 bR = __builtin_bit_cast(bf16x8, lds[kg][n0 + l31]);
      bf16x8 aI = __builtin_bit_cast(bf16x8, lds[16 + kg][m0 + l31]);
      bf16x8 bI = __builtin_bit_cast(bf16x8, lds[16 + kg][n0 + l31]);
      accR = __builtin_amdgcn_mfma_f32_32x32x16_bf16(aR, bR, accR, 0, 0, 0);
      accR = __builtin_amdgcn_mfma_f32_32x32x16_bf16(aI, bI, accR, 0, 0, 0);
      accI = __builtin_amdgcn_mfma_f32_32x32x16_bf16(aR, bI, accI, 0, 0, 0);
    }
    __syncthreads();
  }

  // ---- epilogue: partials -> ws. slot 0 = rr+ii, slot 1 = ri - ri^T ----
  float* wsR = ws + ((size_t)(c * 32 + b) * 2) * 4096;
  float* wsM = wsR + 4096;
  const int jj = n0 + l31;
  #pragma unroll
  for (int r = 0; r < 16; ++r) {
    const int i = m0 + (r & 3) + 8 * (r >> 2) + 4 * lhi;
    wsR[i * 64 + jj] = accR[r];
  }
  float* ldsf = (float*)lds;   // 64*65*4 = 16.6 KB <= 32 KB
  #pragma unroll
  for (int r = 0; r < 16; ++r) {
    const int i = m0 + (r & 3) + 8 * (r >> 2) + 4 * lhi;
    ldsf[i * 65 + jj] = accI[r];
  }
  __syncthreads();
  #pragma unroll
  for (int k = 0; k < 16; ++k) {
    const int e = tid + 256 * k;
    const int i = e >> 6, j = e & 63;
    wsM[e] = ldsf[i * 65 + j] - ldsf[j * 65 + i];
  }
}

// Sum CHUNKS chunk-partials, scale by 1/S. out = real[32][64][64] ++ imag[...].
template<int CHUNKS>
__global__ __launch_bounds__(256) void gram_reduce(
    const float4* __restrict__ ws, float4* __restrict__ out)
{
  const int o = blockIdx.x * 256 + threadIdx.x;   // 65536 float4s
  const int kind = o >> 15;
  const int rem  = o & 32767;
  const int b    = rem >> 10;
  const int e    = rem & 1023;
  const float inv = 1.0f / (float)SEQ;
  float sx = 0.f, sy = 0.f, sz = 0.f, sw = 0.f;
  #pragma unroll
  for (int c = 0; c < CHUNKS; ++c) {
    float4 v = ws[((size_t)(c * 32 + b) * 2 + kind) * 1024 + e];
    sx += v.x; sy += v.y; sz += v.z; sw += v.w;
  }
  float4 r; r.x = sx * inv; r.y = sy * inv; r.z = sz * inv; r.w = sw * inv;
  out[o] = r;
}

extern "C" void kernel_launch(void* const* d_in, const int* in_sizes, int n_in,
                              void* d_out, int out_size, void* d_ws, size_t ws_size,
                              hipStream_t stream) {
  const float* R = (const float*)d_in[0];
  const float* I = (const float*)d_in[1];
  float* out = (float*)d_out;
  float* ws  = (float*)d_ws;

  const size_t need32 = (size_t)32 * 32 * 2 * 4096 * 4;   // 33.6 MB
  if (ws_size >= need32) {
    gram_partial<32><<<BATCH * 32, 256, 0, stream>>>(R, I, ws);
    gram_reduce<32><<<256, 256, 0, stream>>>((const float4*)ws, (float4*)out);
  } else {
    gram_partial<16><<<BATCH * 16, 256, 0, stream>>>(R, I, ws);
    gram_reduce<16><<<256, 256, 0, stream>>>((const float4*)ws, (float4*)out);
  }
}